// Round 8
// baseline (862.859 us; speedup 1.0000x reference)
//
#include <hip/hip_runtime.h>
#include <hip/hip_fp16.h>
#include <math.h>

#define NN 50000
#define EE 800000
#define DFi 8
#define DHc 32
#define Hh 4
#define HCc 128
#define DEe 4
#define DDd 256
#define DOo 4

// ---------------- edge-index dtype detect + convert (+count fused) ----------------
__global__ void detect_kernel(const unsigned int* __restrict__ w, int nwords, int* __restrict__ flag) {
    unsigned int acc = 0;
    for (int i = 2 * threadIdx.x + 1; i < nwords; i += 512) acc |= w[i];
    if (acc) atomicOr(flag, 1);
}

__global__ void convert_count_kernel(const void* __restrict__ buf, const int* __restrict__ flag,
                                     int* __restrict__ EI, int* __restrict__ counts) {
    int i = blockIdx.x * 256 + threadIdx.x;
    if (i >= 2 * EE) return;
    int v = (*flag) ? ((const int*)buf)[i] : (int)(((const long long*)buf)[i]);
    EI[i] = v;
    if (i >= EE) atomicAdd(&counts[v], 1);
}

// edge_attr -> fp16 (4 halves = 8B per edge)
__global__ void ea2h_kernel(const float4* __restrict__ EA4, __half* __restrict__ EAh) {
    int e = blockIdx.x * 256 + threadIdx.x;
    if (e >= EE) return;
    float4 a = EA4[e];
    __half2* o = reinterpret_cast<__half2*>(EAh + e * 4);
    o[0] = __floats2half2_rn(a.x, a.y);
    o[1] = __floats2half2_rn(a.z, a.w);
}

// ---------------- CSR build ----------------
__global__ void scanA_kernel(const int* __restrict__ counts, int* __restrict__ roff,
                             int* __restrict__ bsum, int M) {
    __shared__ int sd[256];
    int t = threadIdx.x;
    int idx = blockIdx.x * 256 + t;
    int v = (idx < M) ? counts[idx] : 0;
    sd[t] = v;
    __syncthreads();
    for (int off = 1; off < 256; off <<= 1) {
        int x = (t >= off) ? sd[t - off] : 0;
        __syncthreads();
        sd[t] += x;
        __syncthreads();
    }
    if (idx < M) roff[idx] = sd[t] - v;      // exclusive
    if (t == 255) bsum[blockIdx.x] = sd[255];
}

__global__ void scanB_kernel(const int* __restrict__ bsum, int* __restrict__ boff, int nb) {
    __shared__ int sd[256];
    int t = threadIdx.x;
    int v = (t < nb) ? bsum[t] : 0;
    sd[t] = v;
    __syncthreads();
    for (int off = 1; off < 256; off <<= 1) {
        int x = (t >= off) ? sd[t - off] : 0;
        __syncthreads();
        sd[t] += x;
        __syncthreads();
    }
    boff[t] = sd[t] - v;                     // exclusive
}

__global__ void scanC_kernel(int* __restrict__ roff, const int* __restrict__ boff, int M) {
    int idx = blockIdx.x * 256 + threadIdx.x;
    if (idx < M) roff[idx] += boff[idx >> 8];
}

__global__ void fill_kernel(const int* __restrict__ EI, const int* __restrict__ roff,
                            int* __restrict__ cursor, long long* __restrict__ ce) {
    int e = blockIdx.x * 256 + threadIdx.x;
    if (e >= EE) return;
    int d = EI[EE + e];
    int s = EI[e];
    int pos = atomicAdd(&cursor[d], 1);
    ce[roff[d] + pos] = ((long long)e << 32) | (unsigned int)s;
}

// deterministic order within each segment: sort by packed key (eid in high bits).
__global__ __launch_bounds__(256) void sortw_kernel(const int* __restrict__ roff,
                                                    long long* __restrict__ ce) {
    const int n = blockIdx.x * 4 + (threadIdx.x >> 6);
    if (n >= NN) return;
    const int lane = threadIdx.x & 63;
    const int a = roff[n];
    const int d = roff[n + 1] - a;
    if (d <= 1) return;
    if (d <= 64) {
        long long key = (lane < d) ? ce[a + lane] : 0x7fffffffffffffffLL;
#pragma unroll
        for (int k = 2; k <= 64; k <<= 1) {
#pragma unroll
            for (int j = k >> 1; j > 0; j >>= 1) {
                long long o = __shfl_xor(key, j);
                bool up = ((lane & k) == 0);
                bool lower = ((lane & j) == 0);
                long long mn = (o < key) ? o : key;
                long long mx = (o < key) ? key : o;
                key = (lower == up) ? mn : mx;
            }
        }
        if (lane < d) ce[a + lane] = key;
    } else if (lane == 0) {
        for (int i2 = a + 1; i2 < a + d; i2++) {
            long long kk = ce[i2];
            int j2 = i2 - 1;
            while (j2 >= a && ce[j2] > kk) { ce[j2 + 1] = ce[j2]; j2--; }
            ce[j2 + 1] = kk;
        }
    }
}

// ---------------- node transform: XLh = fp16(x@Wl+bl), XR = x@Wr+br, per-head norms ----------
template <int IN>
__global__ __launch_bounds__(128) void transform_kernel(
    const float* __restrict__ Xin, const float* __restrict__ Wl, const float* __restrict__ bl,
    const float* __restrict__ Wr, const float* __restrict__ br,
    __half* __restrict__ XLh, float* __restrict__ XR,
    float* __restrict__ NLn, float* __restrict__ NRn) {
    const int t = threadIdx.x;
    float wl[IN], wr[IN];
#pragma unroll
    for (int k = 0; k < IN; k++) { wl[k] = Wl[k * HCc + t]; wr[k] = Wr[k * HCc + t]; }
    const float blv = bl[t], brv = br[t];
    __shared__ float xst[16][IN];
    const int nbeg = blockIdx.x * 16;
    for (int idx = t; idx < 16 * IN; idx += 128) {
        int r = idx / IN, cc = idx % IN;
        int n = nbeg + r;
        xst[r][cc] = (n < NN) ? Xin[n * IN + cc] : 0.f;
    }
    __syncthreads();
#pragma unroll 4
    for (int r = 0; r < 16; ++r) {
        int n = nbeg + r;
        if (n >= NN) break;
        float al = blv, ar = brv;
#pragma unroll
        for (int k = 0; k < IN; k++) { float xv = xst[r][k]; al = fmaf(xv, wl[k], al); ar = fmaf(xv, wr[k], ar); }
        XLh[n * HCc + t] = __float2half(al);
        XR[n * HCc + t] = ar;
        float sl = al * al, sr = ar * ar;
#pragma unroll
        for (int msk = 1; msk < 32; msk <<= 1) { sl += __shfl_xor(sl, msk); sr += __shfl_xor(sr, msk); }
        if ((t & 31) == 0) { NLn[n * 4 + (t >> 5)] = sqrtf(sl); NRn[n * 4 + (t >> 5)] = sqrtf(sr); }
    }
}

// ---------------- per-node max of in-neighbor norms: edge-parallel atomicMax ----------------
// int-punned atomicMax on non-negative floats is exact & order-invariant (deterministic).
__global__ void normmax_kernel(const int* __restrict__ EI, const float* __restrict__ NLn,
                               int* __restrict__ mxi) {
    int e = blockIdx.x * 256 + threadIdx.x;
    if (e >= EE) return;
    int s = EI[e], d = EI[EE + e];
    float4 nj = reinterpret_cast<const float4*>(NLn)[s];
    atomicMax(mxi + d * 4 + 0, __float_as_int(nj.x));
    atomicMax(mxi + d * 4 + 1, __float_as_int(nj.y));
    atomicMax(mxi + d * 4 + 2, __float_as_int(nj.z));
    atomicMax(mxi + d * 4 + 3, __float_as_int(nj.w));
}

__global__ void invd_kernel(const float* __restrict__ NRn, const int* __restrict__ mxi,
                            float* __restrict__ invd) {
    int idx = blockIdx.x * 256 + threadIdx.x;
    if (idx >= NN * 4) return;
    float mx = __int_as_float(mxi[idx]);
    invd[idx] = 1.0f / (4.0f * (NRn[idx] + mx) + 1e-12f);
}

__device__ inline float4 h8tof4(uint2 r) {
    __half2 p0 = *reinterpret_cast<const __half2*>(&r.x);
    __half2 p1 = *reinterpret_cast<const __half2*>(&r.y);
    float2 lo = __half22float2(p0), hi = __half22float2(p1);
    return make_float4(lo.x, lo.y, hi.x, hi.y);
}

// ---------------- fused per-node GAT layer (persistent waves, depth-3 pipeline) ------------
// wave = one node, grid-strided. lane = (g, c): c = lane&31 owns flat channels 4c..4c+3
// (head = c>>3); g = lane>>5 picks edge stream (slots g, g+2, ...).
__global__ __launch_bounds__(256) void gat_kernel(
    const __half* __restrict__ XLh, const float* __restrict__ XR,
    const float* __restrict__ invd,
    const int* __restrict__ roff, const long long* __restrict__ ce,
    const __half* __restrict__ EAh, const float* __restrict__ We,
    const float* __restrict__ att, const float* __restrict__ bo,
    float* __restrict__ Hout) {
    const int lane = threadIdx.x & 63;
    const int wslot = blockIdx.x * 4 + (threadIdx.x >> 6);
    const int NW = gridDim.x * 4;
    const int c = lane & 31;
    const int g = lane >> 5;
    const int h = c >> 3;

    const uint2*  XLu2 = reinterpret_cast<const uint2*>(XLh);
    const uint2*  EAu2 = reinterpret_cast<const uint2*>(EAh);
    const float4* XR4 = reinterpret_cast<const float4*>(XR);
    const float4* We4 = reinterpret_cast<const float4*>(We);
    const float4* at4 = reinterpret_cast<const float4*>(att);
    const float4* bo4 = reinterpret_cast<const float4*>(bo);
    float4* Ho4 = reinterpret_cast<float4*>(Hout);

    const float4 w0 = We4[c], w1 = We4[32 + c], w2 = We4[64 + c], w3 = We4[96 + c];
    const float4 at = at4[c];

    for (int i = wslot; i < NN; i += NW) {
        const int base = roff[i];
        const int deg = roff[i + 1] - base;

        if (deg == 0) {
            if (lane < 8) {
                float4 b = bo4[lane];
                float4 r;
                r.x = b.x > 0.f ? b.x : 0.01f * b.x;
                r.y = b.y > 0.f ? b.y : 0.01f * b.y;
                r.z = b.z > 0.f ? b.z : 0.01f * b.z;
                r.w = b.w > 0.f ? b.w : 0.01f * b.w;
                Ho4[i * 8 + lane] = r;
            }
            continue;
        }

        const float invD = invd[i * 4 + h];
        const float4 xi = XR4[i * 32 + c];
        float srun = 0.f;
        float4 acc = make_float4(0.f, 0.f, 0.f, 0.f);

#define BODY(XR_, ER_, K)                                                         \
        {                                                                         \
            float4 xj = h8tof4(XR_);                                              \
            float4 a4 = h8tof4(ER_);                                              \
            float e0 = a4.x * w0.x; e0 = fmaf(a4.y, w1.x, e0);                    \
            e0 = fmaf(a4.z, w2.x, e0); e0 = fmaf(a4.w, w3.x, e0);                 \
            float e1 = a4.x * w0.y; e1 = fmaf(a4.y, w1.y, e1);                    \
            e1 = fmaf(a4.z, w2.y, e1); e1 = fmaf(a4.w, w3.y, e1);                 \
            float e2 = a4.x * w0.z; e2 = fmaf(a4.y, w1.z, e2);                    \
            e2 = fmaf(a4.z, w2.z, e2); e2 = fmaf(a4.w, w3.z, e2);                 \
            float e3 = a4.x * w0.w; e3 = fmaf(a4.y, w1.w, e3);                    \
            e3 = fmaf(a4.z, w2.w, e3); e3 = fmaf(a4.w, w3.w, e3);                 \
            float s0 = xi.x + xj.x + e0; s0 = s0 > 0.f ? s0 : 0.2f * s0;          \
            float s1 = xi.y + xj.y + e1; s1 = s1 > 0.f ? s1 : 0.2f * s1;          \
            float s2 = xi.z + xj.z + e2; s2 = s2 > 0.f ? s2 : 0.2f * s2;          \
            float s3 = xi.w + xj.w + e3; s3 = s3 > 0.f ? s3 : 0.2f * s3;          \
            float pp = s0 * at.x; pp = fmaf(s1, at.y, pp);                        \
            pp = fmaf(s2, at.z, pp); pp = fmaf(s3, at.w, pp);                     \
            pp += __shfl_xor(pp, 1); pp += __shfl_xor(pp, 2);                     \
            pp += __shfl_xor(pp, 4);                                              \
            float z = __expf(fminf(pp * invD, 60.f));                             \
            z = ((K) < deg) ? z : 0.f;                                            \
            srun += z;                                                            \
            acc.x = fmaf(z, xj.x, acc.x);                                         \
            acc.y = fmaf(z, xj.y, acc.y);                                         \
            acc.z = fmaf(z, xj.z, acc.z);                                         \
            acc.w = fmaf(z, xj.w, acc.w);                                         \
        }

        if (deg <= 64) {
            // stash edge list in regs (one 8B load per lane)
            int jreg = 0, ereg = 0;
            if (lane < deg) {
                long long v = ce[base + lane];
                jreg = (int)(v & 0xffffffffLL);
                ereg = (int)(v >> 32);
            }
#define ISSUE(XR_, ER_, K)                                                        \
            {                                                                     \
                int kc = ((K) < deg) ? (K) : 0;                                   \
                int jx = __shfl(jreg, kc);                                        \
                int ex = __shfl(ereg, kc);                                        \
                XR_ = XLu2[jx * 32 + c];                                          \
                ER_ = EAu2[ex];                                                   \
            }
            const int nsteps = (deg + 1) >> 1;
            uint2 xA, eA, xB, eB, xC, eC;
            ISSUE(xA, eA, g);
            ISSUE(xB, eB, g + 2);
            ISSUE(xC, eC, g + 4);
            for (int s = 0; s < nsteps; s += 3) {
                uint2 xD, eD, xE, eE, xF, eF;
                ISSUE(xD, eD, g + 2 * (s + 3));
                ISSUE(xE, eE, g + 2 * (s + 4));
                ISSUE(xF, eF, g + 2 * (s + 5));
                BODY(xA, eA, g + 2 * s);
                if (s + 1 < nsteps) BODY(xB, eB, g + 2 * (s + 1));
                if (s + 2 < nsteps) BODY(xC, eC, g + 2 * (s + 2));
                xA = xD; eA = eD; xB = xE; eB = eE; xC = xF; eC = eF;
            }
#undef ISSUE
        } else {
            // generic fallback (deg > 64): direct loads, depth-1
            for (int kk = g; kk < deg; kk += 2) {
                long long v = ce[base + kk];
                int jc = (int)(v & 0xffffffffLL);
                int ec = (int)(v >> 32);
                uint2 xr = XLu2[jc * 32 + c];
                uint2 er = EAu2[ec];
                BODY(xr, er, kk);
            }
        }
#undef BODY

        // merge the 2 streams (pure sums)
        srun += __shfl_xor(srun, 32);
        acc.x += __shfl_xor(acc.x, 32);
        acc.y += __shfl_xor(acc.y, 32);
        acc.z += __shfl_xor(acc.z, 32);
        acc.w += __shfl_xor(acc.w, 32);
        float inv = 1.0f / (srun + 1e-16f);
        float a0 = acc.x * inv, a1 = acc.y * inv, a2 = acc.z * inv, a3 = acc.w * inv;
        // head mean: sum over c bits 3,4 (heads)
        a0 += __shfl_xor(a0, 8); a0 += __shfl_xor(a0, 16);
        a1 += __shfl_xor(a1, 8); a1 += __shfl_xor(a1, 16);
        a2 += __shfl_xor(a2, 8); a2 += __shfl_xor(a2, 16);
        a3 += __shfl_xor(a3, 8); a3 += __shfl_xor(a3, 16);

        if (lane < 8) {
            float4 b = bo4[lane];
            float4 r;
            r.x = fmaf(0.25f, a0, b.x); r.x = r.x > 0.f ? r.x : 0.01f * r.x;
            r.y = fmaf(0.25f, a1, b.y); r.y = r.y > 0.f ? r.y : 0.01f * r.y;
            r.z = fmaf(0.25f, a2, b.z); r.z = r.z > 0.f ? r.z : 0.01f * r.z;
            r.w = fmaf(0.25f, a3, b.w); r.w = r.w > 0.f ? r.w : 0.01f * r.w;
            Ho4[i * 8 + lane] = r;
        }
    }
}

// ---------------- MLP head ----------------
__global__ __launch_bounds__(256) void mlp_kernel(
    const float* __restrict__ Hin, const float* __restrict__ Wd1, const float* __restrict__ bd1,
    const float* __restrict__ Wd2, const float* __restrict__ bd2, float* __restrict__ out) {
    const int lane = threadIdx.x & 63;
    const int chunk = __builtin_amdgcn_readfirstlane(threadIdx.x >> 6);
    const int nb = blockIdx.x * 64;
    int node = nb + lane;
    int nclamp = node < NN ? node : NN - 1;

    float h[32];
    const float4* H4 = reinterpret_cast<const float4*>(Hin);
#pragma unroll
    for (int r = 0; r < 8; ++r) {
        float4 t = H4[nclamp * 8 + r];
        h[4 * r] = t.x; h[4 * r + 1] = t.y; h[4 * r + 2] = t.z; h[4 * r + 3] = t.w;
    }

    float o0 = 0.f, o1 = 0.f, o2 = 0.f, o3 = 0.f;
    const int dbase = chunk * 64;
    for (int t = 0; t < 4; ++t) {
        float acc[16];
#pragma unroll
        for (int j = 0; j < 16; ++j) acc[j] = bd1[dbase + t * 16 + j];
#pragma unroll 8
        for (int k = 0; k < 32; ++k) {
            const float* wr = Wd1 + k * DDd + dbase + t * 16;
#pragma unroll
            for (int j = 0; j < 16; ++j) acc[j] = fmaf(h[k], wr[j], acc[j]);
        }
#pragma unroll
        for (int j = 0; j < 16; ++j) {
            float hd = acc[j];
            hd = hd > 0.f ? hd : 0.01f * hd;
            int d = dbase + t * 16 + j;
            o0 = fmaf(hd, Wd2[d * 4 + 0], o0);
            o1 = fmaf(hd, Wd2[d * 4 + 1], o1);
            o2 = fmaf(hd, Wd2[d * 4 + 2], o2);
            o3 = fmaf(hd, Wd2[d * 4 + 3], o3);
        }
    }

    __shared__ float4 red[4][64];
    red[chunk][lane] = make_float4(o0, o1, o2, o3);
    __syncthreads();
    if (threadIdx.x < 64 && nb + (int)threadIdx.x < NN) {
        float4 r0 = red[0][threadIdx.x], r1 = red[1][threadIdx.x];
        float4 r2 = red[2][threadIdx.x], r3 = red[3][threadIdx.x];
        float4 o;
        o.x = r0.x + r1.x + r2.x + r3.x + bd2[0];
        o.y = r0.y + r1.y + r2.y + r3.y + bd2[1];
        o.z = r0.z + r1.z + r2.z + r3.z + bd2[2];
        o.w = r0.w + r1.w + r2.w + r3.w + bd2[3];
        reinterpret_cast<float4*>(out)[nb + threadIdx.x] = o;
    }
}

extern "C" void kernel_launch(void* const* d_in, const int* in_sizes, int n_in,
                              void* d_out, int out_size, void* d_ws, size_t ws_size,
                              hipStream_t stream) {
    const float* x    = (const float*)d_in[0];
    const void*  eraw = d_in[1];
    const float* ea   = (const float*)d_in[2];
    const float* Wl0  = (const float*)d_in[3];
    const float* bl0  = (const float*)d_in[4];
    const float* Wr0  = (const float*)d_in[5];
    const float* br0  = (const float*)d_in[6];
    const float* We0  = (const float*)d_in[7];
    const float* att0 = (const float*)d_in[8];
    const float* bo0  = (const float*)d_in[9];
    const float* Wl   = (const float*)d_in[10];
    const float* bl   = (const float*)d_in[11];
    const float* Wr   = (const float*)d_in[12];
    const float* br   = (const float*)d_in[13];
    const float* We   = (const float*)d_in[14];
    const float* att  = (const float*)d_in[15];
    const float* bo   = (const float*)d_in[16];
    const float* Wd1  = (const float*)d_in[17];
    const float* bd1  = (const float*)d_in[18];
    const float* Wd2  = (const float*)d_in[19];
    const float* bd2  = (const float*)d_in[20];
    float* out = (float*)d_out;

    char* p = (char*)d_ws;
    auto alloc = [&](size_t bytes) { void* r = (void*)p; p += (bytes + 255) & ~(size_t)255; return r; };
    int*       EI     = (int*)alloc((size_t)2 * EE * 4);
    int*       counts = (int*)alloc((size_t)(NN + 1) * 4);
    int*       roff   = (int*)alloc((size_t)(NN + 1) * 4);
    int*       bsum   = (int*)alloc(256 * 4);
    int*       boff   = (int*)alloc(256 * 4);
    int*       cursor = (int*)alloc((size_t)NN * 4);
    long long* ce     = (long long*)alloc((size_t)EE * 8);
    int*       flag   = (int*)alloc(256);
    __half*    XLh    = (__half*)alloc((size_t)NN * HCc * 2);
    __half*    EAh    = (__half*)alloc((size_t)EE * 4 * 2);
    float*     XRb    = (float*)alloc((size_t)NN * HCc * 4);
    float*     NLn    = (float*)alloc((size_t)NN * 4 * 4);
    float*     NRn    = (float*)alloc((size_t)NN * 4 * 4);
    int*       mxi    = (int*)alloc((size_t)NN * 4 * 4);
    float*     invd   = (float*)alloc((size_t)NN * 4 * 4);
    float*     HA     = (float*)alloc((size_t)NN * DHc * 4);
    float*     HB     = (float*)alloc((size_t)NN * DHc * 4);

    (void)hipMemsetAsync(counts, 0, (size_t)(NN + 1) * 4, stream);
    (void)hipMemsetAsync(cursor, 0, (size_t)NN * 4, stream);
    (void)hipMemsetAsync(flag, 0, 4, stream);

    detect_kernel<<<1, 256, 0, stream>>>((const unsigned int*)eraw, 8192, flag);
    convert_count_kernel<<<(2 * EE + 255) / 256, 256, 0, stream>>>(eraw, flag, EI, counts);
    ea2h_kernel<<<(EE + 255) / 256, 256, 0, stream>>>((const float4*)ea, EAh);
    const int M = NN + 1;
    const int NBLK = (M + 255) / 256;
    scanA_kernel<<<NBLK, 256, 0, stream>>>(counts, roff, bsum, M);
    scanB_kernel<<<1, 256, 0, stream>>>(bsum, boff, NBLK);
    scanC_kernel<<<NBLK, 256, 0, stream>>>(roff, boff, M);
    fill_kernel<<<(EE + 255) / 256, 256, 0, stream>>>(EI, roff, cursor, ce);
    sortw_kernel<<<(NN + 3) / 4, 256, 0, stream>>>(roff, ce);

    const int gT = (NN + 15) / 16;   // 3125 blocks
    const int gG = 2048;             // persistent gat: 8192 waves
    const int gE = (EE + 255) / 256;
    const int gI = (NN * 4 + 255) / 256;

#define LAYER(XIN, WLp, BLp, WRp, BRp, WEp, ATTp, BOp, HOUT, TIN)                            \
    transform_kernel<TIN><<<gT, 128, 0, stream>>>(XIN, WLp, BLp, WRp, BRp, XLh, XRb, NLn, NRn); \
    (void)hipMemsetAsync(mxi, 0, (size_t)NN * 4 * 4, stream);                                \
    normmax_kernel<<<gE, 256, 0, stream>>>(EI, NLn, mxi);                                    \
    invd_kernel<<<gI, 256, 0, stream>>>(NRn, mxi, invd);                                     \
    gat_kernel<<<gG, 256, 0, stream>>>(XLh, XRb, invd, roff, ce, EAh, WEp, ATTp, BOp, HOUT);

    LAYER(x,  Wl0, bl0, Wr0, br0, We0, att0, bo0, HA, DFi)
    LAYER(HA, Wl, bl, Wr, br, We, att, bo, HB, DHc)
    LAYER(HB, Wl + DHc * HCc, bl + HCc, Wr + DHc * HCc, br + HCc,
          We + DEe * HCc, att + Hh * DHc, bo + DHc, HA, DHc)
#undef LAYER

    mlp_kernel<<<(NN + 63) / 64, 256, 0, stream>>>(HA, Wd1, bd1, Wd2, bd2, out);
}

// Round 9
// 491.225 us; speedup vs baseline: 1.7565x; 1.7565x over previous
//
#include <hip/hip_runtime.h>
#include <hip/hip_fp16.h>
#include <math.h>

#define NN 50000
#define EE 800000
#define DFi 8
#define DHc 32
#define Hh 4
#define HCc 128
#define DEe 4
#define DDd 256
#define DOo 4

// ---------------- edge-index dtype detect + convert (+count fused) ----------------
__global__ void detect_kernel(const unsigned int* __restrict__ w, int nwords, int* __restrict__ flag) {
    unsigned int acc = 0;
    for (int i = 2 * threadIdx.x + 1; i < nwords; i += 512) acc |= w[i];
    if (acc) atomicOr(flag, 1);
}

__global__ void convert_count_kernel(const void* __restrict__ buf, const int* __restrict__ flag,
                                     int* __restrict__ EI, int* __restrict__ counts) {
    int i = blockIdx.x * 256 + threadIdx.x;
    if (i >= 2 * EE) return;
    int v = (*flag) ? ((const int*)buf)[i] : (int)(((const long long*)buf)[i]);
    EI[i] = v;
    if (i >= EE) atomicAdd(&counts[v], 1);
}

// edge_attr -> fp16 (4 halves = 8B per edge)
__global__ void ea2h_kernel(const float4* __restrict__ EA4, __half* __restrict__ EAh) {
    int e = blockIdx.x * 256 + threadIdx.x;
    if (e >= EE) return;
    float4 a = EA4[e];
    __half2* o = reinterpret_cast<__half2*>(EAh + e * 4);
    o[0] = __floats2half2_rn(a.x, a.y);
    o[1] = __floats2half2_rn(a.z, a.w);
}

// ---------------- CSR build ----------------
__global__ void scanA_kernel(const int* __restrict__ counts, int* __restrict__ roff,
                             int* __restrict__ bsum, int M) {
    __shared__ int sd[256];
    int t = threadIdx.x;
    int idx = blockIdx.x * 256 + t;
    int v = (idx < M) ? counts[idx] : 0;
    sd[t] = v;
    __syncthreads();
    for (int off = 1; off < 256; off <<= 1) {
        int x = (t >= off) ? sd[t - off] : 0;
        __syncthreads();
        sd[t] += x;
        __syncthreads();
    }
    if (idx < M) roff[idx] = sd[t] - v;      // exclusive
    if (t == 255) bsum[blockIdx.x] = sd[255];
}

__global__ void scanB_kernel(const int* __restrict__ bsum, int* __restrict__ boff, int nb) {
    __shared__ int sd[256];
    int t = threadIdx.x;
    int v = (t < nb) ? bsum[t] : 0;
    sd[t] = v;
    __syncthreads();
    for (int off = 1; off < 256; off <<= 1) {
        int x = (t >= off) ? sd[t - off] : 0;
        __syncthreads();
        sd[t] += x;
        __syncthreads();
    }
    boff[t] = sd[t] - v;                     // exclusive
}

__global__ void scanC_kernel(int* __restrict__ roff, const int* __restrict__ boff, int M) {
    int idx = blockIdx.x * 256 + threadIdx.x;
    if (idx < M) roff[idx] += boff[idx >> 8];
}

__global__ void fill_kernel(const int* __restrict__ EI, const int* __restrict__ roff,
                            int* __restrict__ cursor, long long* __restrict__ ce) {
    int e = blockIdx.x * 256 + threadIdx.x;
    if (e >= EE) return;
    int d = EI[EE + e];
    int s = EI[e];
    int pos = atomicAdd(&cursor[d], 1);
    ce[roff[d] + pos] = ((long long)e << 32) | (unsigned int)s;
}

// deterministic order within each segment: sort by packed key (eid in high bits).
__global__ __launch_bounds__(256) void sortw_kernel(const int* __restrict__ roff,
                                                    long long* __restrict__ ce) {
    const int n = blockIdx.x * 4 + (threadIdx.x >> 6);
    if (n >= NN) return;
    const int lane = threadIdx.x & 63;
    const int a = roff[n];
    const int d = roff[n + 1] - a;
    if (d <= 1) return;
    if (d <= 64) {
        long long key = (lane < d) ? ce[a + lane] : 0x7fffffffffffffffLL;
#pragma unroll
        for (int k = 2; k <= 64; k <<= 1) {
#pragma unroll
            for (int j = k >> 1; j > 0; j >>= 1) {
                long long o = __shfl_xor(key, j);
                bool up = ((lane & k) == 0);
                bool lower = ((lane & j) == 0);
                long long mn = (o < key) ? o : key;
                long long mx = (o < key) ? key : o;
                key = (lower == up) ? mn : mx;
            }
        }
        if (lane < d) ce[a + lane] = key;
    } else if (lane == 0) {
        for (int i2 = a + 1; i2 < a + d; i2++) {
            long long kk = ce[i2];
            int j2 = i2 - 1;
            while (j2 >= a && ce[j2] > kk) { ce[j2 + 1] = ce[j2]; j2--; }
            ce[j2 + 1] = kk;
        }
    }
}

// ---------------- node transform: XLh = fp16(x@Wl+bl), XR = x@Wr+br, per-head norms ----------
template <int IN>
__global__ __launch_bounds__(128) void transform_kernel(
    const float* __restrict__ Xin, const float* __restrict__ Wl, const float* __restrict__ bl,
    const float* __restrict__ Wr, const float* __restrict__ br,
    __half* __restrict__ XLh, float* __restrict__ XR,
    float* __restrict__ NLn, float* __restrict__ NRn) {
    const int t = threadIdx.x;
    float wl[IN], wr[IN];
#pragma unroll
    for (int k = 0; k < IN; k++) { wl[k] = Wl[k * HCc + t]; wr[k] = Wr[k * HCc + t]; }
    const float blv = bl[t], brv = br[t];
    __shared__ float xst[16][IN];
    const int nbeg = blockIdx.x * 16;
    for (int idx = t; idx < 16 * IN; idx += 128) {
        int r = idx / IN, cc = idx % IN;
        int n = nbeg + r;
        xst[r][cc] = (n < NN) ? Xin[n * IN + cc] : 0.f;
    }
    __syncthreads();
#pragma unroll 4
    for (int r = 0; r < 16; ++r) {
        int n = nbeg + r;
        if (n >= NN) break;
        float al = blv, ar = brv;
#pragma unroll
        for (int k = 0; k < IN; k++) { float xv = xst[r][k]; al = fmaf(xv, wl[k], al); ar = fmaf(xv, wr[k], ar); }
        XLh[n * HCc + t] = __float2half(al);
        XR[n * HCc + t] = ar;
        float sl = al * al, sr = ar * ar;
#pragma unroll
        for (int msk = 1; msk < 32; msk <<= 1) { sl += __shfl_xor(sl, msk); sr += __shfl_xor(sr, msk); }
        if ((t & 31) == 0) { NLn[n * 4 + (t >> 5)] = sqrtf(sl); NRn[n * 4 + (t >> 5)] = sqrtf(sr); }
    }
}

__device__ inline float4 h8tof4(uint2 r) {
    __half2 p0 = *reinterpret_cast<const __half2*>(&r.x);
    __half2 p1 = *reinterpret_cast<const __half2*>(&r.y);
    float2 lo = __half22float2(p0), hi = __half22float2(p1);
    return make_float4(lo.x, lo.y, hi.x, hi.y);
}

// ---------------- fused per-node GAT layer (persistent waves, depth-4 pipeline) ------------
// wave = one node, grid-strided. lane = (g, c): c = lane&31 owns flat channels 4c..4c+3
// (head = c>>3); g = lane>>5 picks edge stream (slots g, g+2, ...).
// phase-2 prologue loads are issued BEFORE the phase-1 butterfly to overlap latency.
__global__ __launch_bounds__(256) void gat_kernel(
    const __half* __restrict__ XLh, const float* __restrict__ XR,
    const float* __restrict__ NLn, const float* __restrict__ NRn,
    const int* __restrict__ roff, const long long* __restrict__ ce,
    const __half* __restrict__ EAh, const float* __restrict__ We,
    const float* __restrict__ att, const float* __restrict__ bo,
    float* __restrict__ Hout) {
    const int lane = threadIdx.x & 63;
    const int wslot = blockIdx.x * 4 + (threadIdx.x >> 6);
    const int NW = gridDim.x * 4;
    const int c = lane & 31;
    const int g = lane >> 5;
    const int h = c >> 3;

    const uint2*  XLu2 = reinterpret_cast<const uint2*>(XLh);
    const uint2*  EAu2 = reinterpret_cast<const uint2*>(EAh);
    const float4* XR4 = reinterpret_cast<const float4*>(XR);
    const float4* NL4 = reinterpret_cast<const float4*>(NLn);
    const float4* We4 = reinterpret_cast<const float4*>(We);
    const float4* at4 = reinterpret_cast<const float4*>(att);
    const float4* bo4 = reinterpret_cast<const float4*>(bo);
    float4* Ho4 = reinterpret_cast<float4*>(Hout);

    const float4 w0 = We4[c], w1 = We4[32 + c], w2 = We4[64 + c], w3 = We4[96 + c];
    const float4 at = at4[c];

    for (int i = wslot; i < NN; i += NW) {
        const int base = roff[i];
        const int deg = roff[i + 1] - base;

        if (deg == 0) {
            if (lane < 8) {
                float4 b = bo4[lane];
                float4 r;
                r.x = b.x > 0.f ? b.x : 0.01f * b.x;
                r.y = b.y > 0.f ? b.y : 0.01f * b.y;
                r.z = b.z > 0.f ? b.z : 0.01f * b.z;
                r.w = b.w > 0.f ? b.w : 0.01f * b.w;
                Ho4[i * 8 + lane] = r;
            }
            continue;
        }

        const float4 xi = XR4[i * 32 + c];
        float srun = 0.f;
        float4 acc = make_float4(0.f, 0.f, 0.f, 0.f);
        float invD;

#define BODY(XR_, ER_, K)                                                         \
        {                                                                         \
            float4 xj = h8tof4(XR_);                                              \
            float4 a4 = h8tof4(ER_);                                              \
            float e0 = a4.x * w0.x; e0 = fmaf(a4.y, w1.x, e0);                    \
            e0 = fmaf(a4.z, w2.x, e0); e0 = fmaf(a4.w, w3.x, e0);                 \
            float e1 = a4.x * w0.y; e1 = fmaf(a4.y, w1.y, e1);                    \
            e1 = fmaf(a4.z, w2.y, e1); e1 = fmaf(a4.w, w3.y, e1);                 \
            float e2 = a4.x * w0.z; e2 = fmaf(a4.y, w1.z, e2);                    \
            e2 = fmaf(a4.z, w2.z, e2); e2 = fmaf(a4.w, w3.z, e2);                 \
            float e3 = a4.x * w0.w; e3 = fmaf(a4.y, w1.w, e3);                    \
            e3 = fmaf(a4.z, w2.w, e3); e3 = fmaf(a4.w, w3.w, e3);                 \
            float s0 = xi.x + xj.x + e0; s0 = s0 > 0.f ? s0 : 0.2f * s0;          \
            float s1 = xi.y + xj.y + e1; s1 = s1 > 0.f ? s1 : 0.2f * s1;          \
            float s2 = xi.z + xj.z + e2; s2 = s2 > 0.f ? s2 : 0.2f * s2;          \
            float s3 = xi.w + xj.w + e3; s3 = s3 > 0.f ? s3 : 0.2f * s3;          \
            float pp = s0 * at.x; pp = fmaf(s1, at.y, pp);                        \
            pp = fmaf(s2, at.z, pp); pp = fmaf(s3, at.w, pp);                     \
            pp += __shfl_xor(pp, 1); pp += __shfl_xor(pp, 2);                     \
            pp += __shfl_xor(pp, 4);                                              \
            float z = __expf(fminf(pp * invD, 60.f));                             \
            z = ((K) < deg) ? z : 0.f;                                            \
            srun += z;                                                            \
            acc.x = fmaf(z, xj.x, acc.x);                                         \
            acc.y = fmaf(z, xj.y, acc.y);                                         \
            acc.z = fmaf(z, xj.z, acc.z);                                         \
            acc.w = fmaf(z, xj.w, acc.w);                                         \
        }

        if (deg <= 64) {
            // stash edge list in regs (one 8B load per lane)
            int jreg = 0, ereg = 0;
            if (lane < deg) {
                long long v = ce[base + lane];
                jreg = (int)(v & 0xffffffffLL);
                ereg = (int)(v >> 32);
            }
#define ISSUE(XR_, ER_, K)                                                        \
            {                                                                     \
                int kc = ((K) < deg) ? (K) : 0;                                   \
                int jx = __shfl(jreg, kc);                                        \
                int ex = __shfl(ereg, kc);                                        \
                XR_ = XLu2[jx * 32 + c];                                          \
                ER_ = EAu2[ex];                                                   \
            }
            // early-issue the first 4 pipeline slots — independent of the butterfly below
            uint2 xA, eA, xB, eB, xC, eC, xD, eD;
            ISSUE(xA, eA, g);
            ISSUE(xB, eB, g + 2);
            ISSUE(xC, eC, g + 4);
            ISSUE(xD, eD, g + 6);

            // phase 1: Lipschitz max of in-neighbor norms (order-invariant; norms >= 0)
            float4 mx = make_float4(0.f, 0.f, 0.f, 0.f);
            if (lane < deg) mx = NL4[jreg];
#pragma unroll
            for (int msk = 1; msk < 64; msk <<= 1) {
                mx.x = fmaxf(mx.x, __shfl_xor(mx.x, msk));
                mx.y = fmaxf(mx.y, __shfl_xor(mx.y, msk));
                mx.z = fmaxf(mx.z, __shfl_xor(mx.z, msk));
                mx.w = fmaxf(mx.w, __shfl_xor(mx.w, msk));
            }
            float mxh = (h == 0) ? mx.x : (h == 1) ? mx.y : (h == 2) ? mx.z : mx.w;
            invD = 1.0f / (4.0f * (NRn[i * 4 + h] + mxh) + 1e-12f);

            const int nsteps = (deg + 1) >> 1;
            for (int s = 0; s < nsteps; s += 4) {
                uint2 xE, eE, xF, eF, xG, eG, xH, eH;
                ISSUE(xE, eE, g + 2 * (s + 4));
                ISSUE(xF, eF, g + 2 * (s + 5));
                ISSUE(xG, eG, g + 2 * (s + 6));
                ISSUE(xH, eH, g + 2 * (s + 7));
                BODY(xA, eA, g + 2 * s);
                if (s + 1 < nsteps) BODY(xB, eB, g + 2 * (s + 1));
                if (s + 2 < nsteps) BODY(xC, eC, g + 2 * (s + 2));
                if (s + 3 < nsteps) BODY(xD, eD, g + 2 * (s + 3));
                xA = xE; eA = eE; xB = xF; eB = eF;
                xC = xG; eC = eG; xD = xH; eD = eH;
            }
#undef ISSUE
        } else {
            // generic fallback (deg > 64): direct loads, depth-1
            float4 mx = make_float4(0.f, 0.f, 0.f, 0.f);
            for (int k = lane; k < deg; k += 64) {
                long long v = ce[base + k];
                int j = (int)(v & 0xffffffffLL);
                float4 nj = NL4[j];
                mx.x = fmaxf(mx.x, nj.x); mx.y = fmaxf(mx.y, nj.y);
                mx.z = fmaxf(mx.z, nj.z); mx.w = fmaxf(mx.w, nj.w);
            }
#pragma unroll
            for (int msk = 1; msk < 64; msk <<= 1) {
                mx.x = fmaxf(mx.x, __shfl_xor(mx.x, msk));
                mx.y = fmaxf(mx.y, __shfl_xor(mx.y, msk));
                mx.z = fmaxf(mx.z, __shfl_xor(mx.z, msk));
                mx.w = fmaxf(mx.w, __shfl_xor(mx.w, msk));
            }
            float mxh = (h == 0) ? mx.x : (h == 1) ? mx.y : (h == 2) ? mx.z : mx.w;
            invD = 1.0f / (4.0f * (NRn[i * 4 + h] + mxh) + 1e-12f);

            for (int kk = g; kk < deg; kk += 2) {
                long long v = ce[base + kk];
                int jc = (int)(v & 0xffffffffLL);
                int ec = (int)(v >> 32);
                uint2 xr = XLu2[jc * 32 + c];
                uint2 er = EAu2[ec];
                BODY(xr, er, kk);
            }
        }
#undef BODY

        // merge the 2 streams (pure sums)
        srun += __shfl_xor(srun, 32);
        acc.x += __shfl_xor(acc.x, 32);
        acc.y += __shfl_xor(acc.y, 32);
        acc.z += __shfl_xor(acc.z, 32);
        acc.w += __shfl_xor(acc.w, 32);
        float inv = 1.0f / (srun + 1e-16f);
        float a0 = acc.x * inv, a1 = acc.y * inv, a2 = acc.z * inv, a3 = acc.w * inv;
        // head mean: sum over c bits 3,4 (heads)
        a0 += __shfl_xor(a0, 8); a0 += __shfl_xor(a0, 16);
        a1 += __shfl_xor(a1, 8); a1 += __shfl_xor(a1, 16);
        a2 += __shfl_xor(a2, 8); a2 += __shfl_xor(a2, 16);
        a3 += __shfl_xor(a3, 8); a3 += __shfl_xor(a3, 16);

        if (lane < 8) {
            float4 b = bo4[lane];
            float4 r;
            r.x = fmaf(0.25f, a0, b.x); r.x = r.x > 0.f ? r.x : 0.01f * r.x;
            r.y = fmaf(0.25f, a1, b.y); r.y = r.y > 0.f ? r.y : 0.01f * r.y;
            r.z = fmaf(0.25f, a2, b.z); r.z = r.z > 0.f ? r.z : 0.01f * r.z;
            r.w = fmaf(0.25f, a3, b.w); r.w = r.w > 0.f ? r.w : 0.01f * r.w;
            Ho4[i * 8 + lane] = r;
        }
    }
}

// ---------------- MLP head ----------------
__global__ __launch_bounds__(256) void mlp_kernel(
    const float* __restrict__ Hin, const float* __restrict__ Wd1, const float* __restrict__ bd1,
    const float* __restrict__ Wd2, const float* __restrict__ bd2, float* __restrict__ out) {
    const int lane = threadIdx.x & 63;
    const int chunk = __builtin_amdgcn_readfirstlane(threadIdx.x >> 6);
    const int nb = blockIdx.x * 64;
    int node = nb + lane;
    int nclamp = node < NN ? node : NN - 1;

    float h[32];
    const float4* H4 = reinterpret_cast<const float4*>(Hin);
#pragma unroll
    for (int r = 0; r < 8; ++r) {
        float4 t = H4[nclamp * 8 + r];
        h[4 * r] = t.x; h[4 * r + 1] = t.y; h[4 * r + 2] = t.z; h[4 * r + 3] = t.w;
    }

    float o0 = 0.f, o1 = 0.f, o2 = 0.f, o3 = 0.f;
    const int dbase = chunk * 64;
    for (int t = 0; t < 4; ++t) {
        float acc[16];
#pragma unroll
        for (int j = 0; j < 16; ++j) acc[j] = bd1[dbase + t * 16 + j];
#pragma unroll 8
        for (int k = 0; k < 32; ++k) {
            const float* wr = Wd1 + k * DDd + dbase + t * 16;
#pragma unroll
            for (int j = 0; j < 16; ++j) acc[j] = fmaf(h[k], wr[j], acc[j]);
        }
#pragma unroll
        for (int j = 0; j < 16; ++j) {
            float hd = acc[j];
            hd = hd > 0.f ? hd : 0.01f * hd;
            int d = dbase + t * 16 + j;
            o0 = fmaf(hd, Wd2[d * 4 + 0], o0);
            o1 = fmaf(hd, Wd2[d * 4 + 1], o1);
            o2 = fmaf(hd, Wd2[d * 4 + 2], o2);
            o3 = fmaf(hd, Wd2[d * 4 + 3], o3);
        }
    }

    __shared__ float4 red[4][64];
    red[chunk][lane] = make_float4(o0, o1, o2, o3);
    __syncthreads();
    if (threadIdx.x < 64 && nb + (int)threadIdx.x < NN) {
        float4 r0 = red[0][threadIdx.x], r1 = red[1][threadIdx.x];
        float4 r2 = red[2][threadIdx.x], r3 = red[3][threadIdx.x];
        float4 o;
        o.x = r0.x + r1.x + r2.x + r3.x + bd2[0];
        o.y = r0.y + r1.y + r2.y + r3.y + bd2[1];
        o.z = r0.z + r1.z + r2.z + r3.z + bd2[2];
        o.w = r0.w + r1.w + r2.w + r3.w + bd2[3];
        reinterpret_cast<float4*>(out)[nb + threadIdx.x] = o;
    }
}

extern "C" void kernel_launch(void* const* d_in, const int* in_sizes, int n_in,
                              void* d_out, int out_size, void* d_ws, size_t ws_size,
                              hipStream_t stream) {
    const float* x    = (const float*)d_in[0];
    const void*  eraw = d_in[1];
    const float* ea   = (const float*)d_in[2];
    const float* Wl0  = (const float*)d_in[3];
    const float* bl0  = (const float*)d_in[4];
    const float* Wr0  = (const float*)d_in[5];
    const float* br0  = (const float*)d_in[6];
    const float* We0  = (const float*)d_in[7];
    const float* att0 = (const float*)d_in[8];
    const float* bo0  = (const float*)d_in[9];
    const float* Wl   = (const float*)d_in[10];
    const float* bl   = (const float*)d_in[11];
    const float* Wr   = (const float*)d_in[12];
    const float* br   = (const float*)d_in[13];
    const float* We   = (const float*)d_in[14];
    const float* att  = (const float*)d_in[15];
    const float* bo   = (const float*)d_in[16];
    const float* Wd1  = (const float*)d_in[17];
    const float* bd1  = (const float*)d_in[18];
    const float* Wd2  = (const float*)d_in[19];
    const float* bd2  = (const float*)d_in[20];
    float* out = (float*)d_out;

    char* p = (char*)d_ws;
    auto alloc = [&](size_t bytes) { void* r = (void*)p; p += (bytes + 255) & ~(size_t)255; return r; };
    int*       EI     = (int*)alloc((size_t)2 * EE * 4);
    int*       counts = (int*)alloc((size_t)(NN + 1) * 4);
    int*       roff   = (int*)alloc((size_t)(NN + 1) * 4);
    int*       bsum   = (int*)alloc(256 * 4);
    int*       boff   = (int*)alloc(256 * 4);
    int*       cursor = (int*)alloc((size_t)NN * 4);
    long long* ce     = (long long*)alloc((size_t)EE * 8);
    int*       flag   = (int*)alloc(256);
    __half*    XLh    = (__half*)alloc((size_t)NN * HCc * 2);
    __half*    EAh    = (__half*)alloc((size_t)EE * 4 * 2);
    float*     XRb    = (float*)alloc((size_t)NN * HCc * 4);
    float*     NLn    = (float*)alloc((size_t)NN * 4 * 4);
    float*     NRn    = (float*)alloc((size_t)NN * 4 * 4);
    float*     HA     = (float*)alloc((size_t)NN * DHc * 4);
    float*     HB     = (float*)alloc((size_t)NN * DHc * 4);

    (void)hipMemsetAsync(counts, 0, (size_t)(NN + 1) * 4, stream);
    (void)hipMemsetAsync(cursor, 0, (size_t)NN * 4, stream);
    (void)hipMemsetAsync(flag, 0, 4, stream);

    detect_kernel<<<1, 256, 0, stream>>>((const unsigned int*)eraw, 8192, flag);
    convert_count_kernel<<<(2 * EE + 255) / 256, 256, 0, stream>>>(eraw, flag, EI, counts);
    ea2h_kernel<<<(EE + 255) / 256, 256, 0, stream>>>((const float4*)ea, EAh);
    const int M = NN + 1;
    const int NBLK = (M + 255) / 256;
    scanA_kernel<<<NBLK, 256, 0, stream>>>(counts, roff, bsum, M);
    scanB_kernel<<<1, 256, 0, stream>>>(bsum, boff, NBLK);
    scanC_kernel<<<NBLK, 256, 0, stream>>>(roff, boff, M);
    fill_kernel<<<(EE + 255) / 256, 256, 0, stream>>>(EI, roff, cursor, ce);
    sortw_kernel<<<(NN + 3) / 4, 256, 0, stream>>>(roff, ce);

    const int gT = (NN + 15) / 16;   // 3125 blocks
    const int gG = 2048;             // persistent gat: 8192 waves

    // layer 0
    transform_kernel<DFi><<<gT, 128, 0, stream>>>(x, Wl0, bl0, Wr0, br0, XLh, XRb, NLn, NRn);
    gat_kernel<<<gG, 256, 0, stream>>>(XLh, XRb, NLn, NRn, roff, ce, EAh, We0, att0, bo0, HA);
    // layer 1
    transform_kernel<DHc><<<gT, 128, 0, stream>>>(HA, Wl, bl, Wr, br, XLh, XRb, NLn, NRn);
    gat_kernel<<<gG, 256, 0, stream>>>(XLh, XRb, NLn, NRn, roff, ce, EAh, We, att, bo, HB);
    // layer 2
    transform_kernel<DHc><<<gT, 128, 0, stream>>>(HB, Wl + DHc * HCc, bl + HCc, Wr + DHc * HCc, br + HCc,
                                                  XLh, XRb, NLn, NRn);
    gat_kernel<<<gG, 256, 0, stream>>>(XLh, XRb, NLn, NRn, roff, ce, EAh, We + DEe * HCc,
                                       att + Hh * DHc, bo + DHc, HA);
    // MLP head
    mlp_kernel<<<(NN + 63) / 64, 256, 0, stream>>>(HA, Wd1, bd1, Wd2, bd2, out);
}